// Round 1
// baseline (431.233 us; speedup 1.0000x reference)
//
#include <hip/hip_runtime.h>

#define NNODES 262144          // N, power of 2 (2^18)
#define HWPIX  1048576         // H*W = 2^20
#define BC     12              // B*C
#define NGROUP 3

__device__ __forceinline__ float sigm(float x) {
    return 1.0f / (1.0f + __expf(-x));
}

// Kernel 1: per-node contrib_g = sigmoid(attrs . W_g + b_g) * residue,
// packed as float4 {c0, c1, c2, as_float(parent)} so the chain walk needs
// one 16B gather per step. 4 nodes per thread.
__global__ __launch_bounds__(256) void k_contrib(
    const float* __restrict__ attrs,   // (BC, N, 3)
    const float* __restrict__ residue, // (BC, N)
    const int*   __restrict__ parent,  // (BC, N)
    const float* __restrict__ W0, const float* __restrict__ W1,
    const float* __restrict__ W2, const float* __restrict__ b0,
    const float* __restrict__ b1, const float* __restrict__ b2,
    float4* __restrict__ contrib)      // (BC*N)
{
    const float w0 = W0[0], w10 = W1[0], w11 = W1[1], w2 = W2[0];
    const float c0 = b0[0], c1 = b1[0], c2 = b2[0];

    int t = blockIdx.x * blockDim.x + threadIdx.x;   // quad-node index
    // 4 nodes -> 12 attr floats = 3 x float4 (16B aligned: 48B stride)
    const float4* a4 = (const float4*)attrs + (size_t)t * 3;
    float4 A = a4[0], Bv = a4[1], Cv = a4[2];
    float4 r  = ((const float4*)residue)[t];
    int4  par = ((const int4*)parent)[t];

    float4 o0, o1, o2, o3;
    // node 0: attrs {A.x, A.y, A.z}
    o0.x = r.x * sigm(A.x * w0 + c0);
    o0.y = r.x * sigm(A.y * w10 + A.z * w11 + c1);
    o0.z = r.x * sigm(A.y * w2 + c2);
    o0.w = __int_as_float(par.x);
    // node 1: attrs {A.w, Bv.x, Bv.y}
    o1.x = r.y * sigm(A.w * w0 + c0);
    o1.y = r.y * sigm(Bv.x * w10 + Bv.y * w11 + c1);
    o1.z = r.y * sigm(Bv.x * w2 + c2);
    o1.w = __int_as_float(par.y);
    // node 2: attrs {Bv.z, Bv.w, Cv.x}
    o2.x = r.z * sigm(Bv.z * w0 + c0);
    o2.y = r.z * sigm(Bv.w * w10 + Cv.x * w11 + c1);
    o2.z = r.z * sigm(Bv.w * w2 + c2);
    o2.w = __int_as_float(par.z);
    // node 3: attrs {Cv.y, Cv.z, Cv.w}
    o3.x = r.w * sigm(Cv.y * w0 + c0);
    o3.y = r.w * sigm(Cv.z * w10 + Cv.w * w11 + c1);
    o3.z = r.w * sigm(Cv.z * w2 + c2);
    o3.w = __int_as_float(par.w);

    float4* dst = contrib + (size_t)t * 4;
    dst[0] = o0; dst[1] = o1; dst[2] = o2; dst[3] = o3;
}

// Kernel 2: ancestor-chain sum. parent[i] < i and the tree is a random
// recursive tree => expected depth ~ln(N) ~= 12.5, so a direct walk beats
// 18 pointer-jumping passes. One dependent 16B gather per step (parent
// is packed in .w). Working set per tree = 4 MB -> L2-resident.
__global__ __launch_bounds__(256) void k_scan(
    const float4* __restrict__ contrib,  // (BC*N)
    float4* __restrict__ f)              // (BC*N)
{
    int idx = blockIdx.x * blockDim.x + threadIdx.x;  // < BC*N
    int bcbase = idx & ~(NNODES - 1);
    float4 c = contrib[idx];
    float fx = c.x, fy = c.y, fz = c.z;
    int j = __float_as_int(c.w);
    while (j != NNODES) {
        float4 cj = contrib[bcbase + j];
        fx += cj.x; fy += cj.y; fz += cj.z;
        j = __float_as_int(cj.w);
    }
    f[idx] = make_float4(fx, fy, fz, 0.0f);
}

// Kernel 3: pixel gather. 4 pixels/thread: int4 pixel_node load, 4 random
// float4 f-gathers (L2/L3-resident tables), 3 coalesced float4 stores to the
// three group output planes.
__global__ __launch_bounds__(256) void k_gather(
    const float4* __restrict__ f,          // (BC*N)
    const int*    __restrict__ pixel_node, // (BC, HW)
    float* __restrict__ out)               // (BC, 3, HW)
{
    int t = blockIdx.x * blockDim.x + threadIdx.x;   // quad-pixel index
    size_t gp = (size_t)t * 4;
    int bc = (int)(gp >> 20);          // HWPIX = 2^20
    int p  = (int)(gp & (HWPIX - 1));
    int4 pn = ((const int4*)pixel_node)[t];
    const float4* fb = f + ((size_t)bc << 18);   // NNODES = 2^18
    float4 f0 = fb[pn.x], f1 = fb[pn.y], f2 = fb[pn.z], f3 = fb[pn.w];
    float* o = out + (size_t)bc * 3 * HWPIX + p;
    *(float4*)(o)             = make_float4(f0.x, f1.x, f2.x, f3.x);
    *(float4*)(o + HWPIX)     = make_float4(f0.y, f1.y, f2.y, f3.y);
    *(float4*)(o + 2 * HWPIX) = make_float4(f0.z, f1.z, f2.z, f3.z);
}

extern "C" void kernel_launch(void* const* d_in, const int* in_sizes, int n_in,
                              void* d_out, int out_size, void* d_ws, size_t ws_size,
                              hipStream_t stream) {
    const float* attrs      = (const float*)d_in[0];
    const float* residue    = (const float*)d_in[1];
    const float* W0         = (const float*)d_in[2];
    const float* W1         = (const float*)d_in[3];
    const float* W2         = (const float*)d_in[4];
    const float* b0         = (const float*)d_in[5];
    const float* b1         = (const float*)d_in[6];
    const float* b2         = (const float*)d_in[7];
    const int*   parent     = (const int*)d_in[8];
    const int*   pixel_node = (const int*)d_in[9];
    float* out = (float*)d_out;

    const size_t total_nodes = (size_t)BC * NNODES;       // 3,145,728
    float4* contrib = (float4*)d_ws;
    float4* fbuf    = contrib + total_nodes;              // 2 x 50.3 MB in ws

    // Kernel 1: 4 nodes/thread
    {
        int threads = (int)(total_nodes / 4);
        k_contrib<<<threads / 256, 256, 0, stream>>>(
            attrs, residue, parent, W0, W1, W2, b0, b1, b2, contrib);
    }
    // Kernel 2: 1 node/thread chain walk
    {
        int threads = (int)total_nodes;
        k_scan<<<threads / 256, 256, 0, stream>>>(contrib, fbuf);
    }
    // Kernel 3: 4 pixels/thread
    {
        int threads = (int)((size_t)BC * HWPIX / 4);
        k_gather<<<threads / 256, 256, 0, stream>>>(fbuf, pixel_node, out);
    }
}

// Round 2
// 377.776 us; speedup vs baseline: 1.1415x; 1.1415x over previous
//
#include <hip/hip_runtime.h>

#define NNODES 262144          // N = 2^18
#define HWPIX  1048576         // H*W = 2^20
#define BC     12              // B*C

__device__ __forceinline__ float sigm(float x) {
    return 1.0f / (1.0f + __expf(-x));
}

// grid is always a multiple of 8 -> simple bijective XCD swizzle:
// physical blocks 0,8,16,... (XCD 0) get contiguous work chunk [0,q).
__device__ __forceinline__ int xcd_swizzle(int orig, int nwg) {
    int q = nwg >> 3;
    return (orig & 7) * q + (orig >> 3);
}

// Kernel 1: per-node contrib_g = sigmoid(attrs . W_g + b_g) * residue,
// packed as float4 {c0, c1, c2, as_float(parent)} so each chain hop is a
// single 16B gather. 4 nodes/thread, fully vectorized loads.
__global__ __launch_bounds__(256) void k_contrib(
    const float* __restrict__ attrs,   // (BC, N, 3)
    const float* __restrict__ residue, // (BC, N)
    const int*   __restrict__ parent,  // (BC, N)
    const float* __restrict__ W0, const float* __restrict__ W1,
    const float* __restrict__ W2, const float* __restrict__ b0,
    const float* __restrict__ b1, const float* __restrict__ b2,
    float4* __restrict__ contrib)      // (BC*N)
{
    const float w0 = W0[0], w10 = W1[0], w11 = W1[1], w2 = W2[0];
    const float c0 = b0[0], c1 = b1[0], c2 = b2[0];

    int t = blockIdx.x * blockDim.x + threadIdx.x;   // quad-node index
    const float4* a4 = (const float4*)attrs + (size_t)t * 3;
    float4 A = a4[0], Bv = a4[1], Cv = a4[2];
    float4 r  = ((const float4*)residue)[t];
    int4  par = ((const int4*)parent)[t];

    float4 o0, o1, o2, o3;
    o0.x = r.x * sigm(A.x * w0 + c0);
    o0.y = r.x * sigm(A.y * w10 + A.z * w11 + c1);
    o0.z = r.x * sigm(A.y * w2 + c2);
    o0.w = __int_as_float(par.x);
    o1.x = r.y * sigm(A.w * w0 + c0);
    o1.y = r.y * sigm(Bv.x * w10 + Bv.y * w11 + c1);
    o1.z = r.y * sigm(Bv.x * w2 + c2);
    o1.w = __int_as_float(par.y);
    o2.x = r.z * sigm(Bv.z * w0 + c0);
    o2.y = r.z * sigm(Bv.w * w10 + Cv.x * w11 + c1);
    o2.z = r.z * sigm(Bv.w * w2 + c2);
    o2.w = __int_as_float(par.z);
    o3.x = r.w * sigm(Cv.y * w0 + c0);
    o3.y = r.w * sigm(Cv.z * w10 + Cv.w * w11 + c1);
    o3.z = r.w * sigm(Cv.z * w2 + c2);
    o3.w = __int_as_float(par.w);

    float4* dst = contrib + (size_t)t * 4;
    dst[0] = o0; dst[1] = o1; dst[2] = o2; dst[3] = o3;
}

// Kernel 2 (x4 launches, geometric chunks): f[i] = contrib[i] + f[parent[i]].
// parent[i] < i, so chunk [lo,hi) only needs: short in-chunk walk (E~0.85
// hops for hi=4*lo) then ONE gather of finalized f below lo. Cuts total
// random gathers ~6x vs full chain walk.
__global__ __launch_bounds__(256) void k_scan_chunk(
    const float4* __restrict__ contrib,
    float4* __restrict__ ftab,
    int lo, int cnt)                   // nodes [lo, lo+cnt) per tree
{
    int w = xcd_swizzle(blockIdx.x, gridDim.x);
    int bpt = cnt >> 8;                // blocks per tree (cnt/256)
    int bc  = w / bpt;
    int i   = lo + (w % bpt) * 256 + threadIdx.x;
    int bcbase = bc << 18;             // NNODES = 2^18

    float4 c = contrib[bcbase + i];
    float fx = c.x, fy = c.y, fz = c.z;
    int j = __float_as_int(c.w);
    if (lo == 0) {
        while (j != NNODES) {          // full walk (root sentinel)
            float4 cj = contrib[bcbase + j];
            fx += cj.x; fy += cj.y; fz += cj.z;
            j = __float_as_int(cj.w);
        }
    } else {
        while (j >= lo) {              // walk only within chunk
            float4 cj = contrib[bcbase + j];
            fx += cj.x; fy += cj.y; fz += cj.z;
            j = __float_as_int(cj.w);
        }
        float4 fp = ftab[bcbase + j];  // finalized in an earlier launch
        fx += fp.x; fy += fp.y; fz += fp.z;
    }
    ftab[bcbase + i] = make_float4(fx, fy, fz, 0.0f);
}

// Kernel 3: pixel gather, 8 px/thread (8 outstanding 16B gathers/lane for
// latency hiding), XCD-swizzled so each XCD's f-gathers stay in ~1.5 trees.
__global__ __launch_bounds__(256) void k_gather(
    const float4* __restrict__ f,          // (BC*N)
    const int*    __restrict__ pixel_node, // (BC, HW)
    float* __restrict__ out)               // (BC, 3, HW)
{
    int w = xcd_swizzle(blockIdx.x, gridDim.x);
    size_t gp = (size_t)w * 2048 + (size_t)threadIdx.x * 8;
    int bc = (int)(gp >> 20);              // HWPIX = 2^20
    int p  = (int)(gp & (HWPIX - 1));
    const int4* pn4 = (const int4*)(pixel_node + gp);
    int4 pa = pn4[0], pb = pn4[1];
    const float4* fb = f + ((size_t)bc << 18);
    float4 f0 = fb[pa.x], f1 = fb[pa.y], f2 = fb[pa.z], f3 = fb[pa.w];
    float4 f4 = fb[pb.x], f5 = fb[pb.y], f6 = fb[pb.z], f7 = fb[pb.w];
    float* o = out + (size_t)bc * 3 * HWPIX + p;
    *(float4*)(o)                 = make_float4(f0.x, f1.x, f2.x, f3.x);
    *(float4*)(o + 4)             = make_float4(f4.x, f5.x, f6.x, f7.x);
    *(float4*)(o + HWPIX)         = make_float4(f0.y, f1.y, f2.y, f3.y);
    *(float4*)(o + HWPIX + 4)     = make_float4(f4.y, f5.y, f6.y, f7.y);
    *(float4*)(o + 2 * HWPIX)     = make_float4(f0.z, f1.z, f2.z, f3.z);
    *(float4*)(o + 2 * HWPIX + 4) = make_float4(f4.z, f5.z, f6.z, f7.z);
}

extern "C" void kernel_launch(void* const* d_in, const int* in_sizes, int n_in,
                              void* d_out, int out_size, void* d_ws, size_t ws_size,
                              hipStream_t stream) {
    const float* attrs      = (const float*)d_in[0];
    const float* residue    = (const float*)d_in[1];
    const float* W0         = (const float*)d_in[2];
    const float* W1         = (const float*)d_in[3];
    const float* W2         = (const float*)d_in[4];
    const float* b0         = (const float*)d_in[5];
    const float* b1         = (const float*)d_in[6];
    const float* b2         = (const float*)d_in[7];
    const int*   parent     = (const int*)d_in[8];
    const int*   pixel_node = (const int*)d_in[9];
    float* out = (float*)d_out;

    const size_t total_nodes = (size_t)BC * NNODES;       // 3,145,728
    float4* contrib = (float4*)d_ws;                      // 50.3 MB
    float4* ftab    = contrib + total_nodes;              // 50.3 MB

    // Kernel 1: contrib + packed parent (4 nodes/thread)
    k_contrib<<<(int)(total_nodes / 4 / 256), 256, 0, stream>>>(
        attrs, residue, parent, W0, W1, W2, b0, b1, b2, contrib);

    // Kernel 2: geometric chunks [0,4K),[4K,16K),[16K,64K),[64K,256K)
    {
        int bounds[5] = {0, 4096, 16384, 65536, NNODES};
        for (int k = 0; k < 4; ++k) {
            int lo = bounds[k], cnt = bounds[k + 1] - bounds[k];
            int nblk = cnt / 256 * BC;
            k_scan_chunk<<<nblk, 256, 0, stream>>>(contrib, ftab, lo, cnt);
        }
    }

    // Kernel 3: pixel gather (8 px/thread)
    k_gather<<<(int)((size_t)BC * HWPIX / 2048), 256, 0, stream>>>(
        ftab, pixel_node, out);
}

// Round 3
// 354.459 us; speedup vs baseline: 1.2166x; 1.0658x over previous
//
#include <hip/hip_runtime.h>

#define NNODES 262144          // N = 2^18
#define HWPIX  1048576         // H*W = 2^20
#define BC     12              // B*C

typedef _Float16 half4 __attribute__((ext_vector_type(4)));

__device__ __forceinline__ float sigm(float x) {
    return 1.0f / (1.0f + __expf(-x));
}

// bijective XCD swizzle (requires gridDim.x % 8 == 0, true for all our grids)
__device__ __forceinline__ int xcd_swizzle(int orig, int nwg) {
    int q = nwg >> 3;
    return (orig & 7) * q + (orig >> 3);
}

// Kernel 1: contrib_g = sigmoid(attrs . W_g + b_g) * residue, packed as
// float4 {c0,c1,c2,as_float(parent)} -> one 16B gather per chain hop.
__global__ __launch_bounds__(256) void k_contrib(
    const float* __restrict__ attrs,   // (BC, N, 3)
    const float* __restrict__ residue, // (BC, N)
    const int*   __restrict__ parent,  // (BC, N)
    const float* __restrict__ W0, const float* __restrict__ W1,
    const float* __restrict__ W2, const float* __restrict__ b0,
    const float* __restrict__ b1, const float* __restrict__ b2,
    float4* __restrict__ contrib)      // (BC*N)
{
    const float w0 = W0[0], w10 = W1[0], w11 = W1[1], w2 = W2[0];
    const float c0 = b0[0], c1 = b1[0], c2 = b2[0];

    int t = blockIdx.x * blockDim.x + threadIdx.x;   // quad-node index
    const float4* a4 = (const float4*)attrs + (size_t)t * 3;
    float4 A = a4[0], Bv = a4[1], Cv = a4[2];
    float4 r  = ((const float4*)residue)[t];
    int4  par = ((const int4*)parent)[t];

    float4 o0, o1, o2, o3;
    o0.x = r.x * sigm(A.x * w0 + c0);
    o0.y = r.x * sigm(A.y * w10 + A.z * w11 + c1);
    o0.z = r.x * sigm(A.y * w2 + c2);
    o0.w = __int_as_float(par.x);
    o1.x = r.y * sigm(A.w * w0 + c0);
    o1.y = r.y * sigm(Bv.x * w10 + Bv.y * w11 + c1);
    o1.z = r.y * sigm(Bv.x * w2 + c2);
    o1.w = __int_as_float(par.y);
    o2.x = r.z * sigm(Bv.z * w0 + c0);
    o2.y = r.z * sigm(Bv.w * w10 + Cv.x * w11 + c1);
    o2.z = r.z * sigm(Bv.w * w2 + c2);
    o2.w = __int_as_float(par.z);
    o3.x = r.w * sigm(Cv.y * w0 + c0);
    o3.y = r.w * sigm(Cv.z * w10 + Cv.w * w11 + c1);
    o3.z = r.w * sigm(Cv.z * w2 + c2);
    o3.w = __int_as_float(par.w);

    float4* dst = contrib + (size_t)t * 4;
    dst[0] = o0; dst[1] = o1; dst[2] = o2; dst[3] = o3;
}

// Kernel 2 (x4 geometric chunks): f[i] = contrib[i] + f[parent-chain].
// Each thread walks CH independent chains lock-step -> CH outstanding
// dependent gathers per lane (fixes the 1-outstanding/wave MLP starvation
// that made R2's scan ~230us). Inactive chains load index 0 (L1-hot) so the
// loop body stays branch-free and all CH loads issue together.
template<int CH, bool BASE>
__global__ __launch_bounds__(256) void k_scan(
    const float4* __restrict__ contrib,
    half4* __restrict__ ftab,          // fp16 x3 (+pad), 8B/node
    int lo, int cnt)                   // nodes [lo, lo+cnt) per tree
{
    int w = xcd_swizzle(blockIdx.x, gridDim.x);
    const int sub = cnt / CH;          // chains per k-slot per tree
    const int bpt = sub >> 8;          // blocks per tree
    int bc = w / bpt;
    int i0 = lo + (w % bpt) * 256 + threadIdx.x;
    const float4* C = contrib + ((size_t)bc << 18);
    half4* F = ftab + ((size_t)bc << 18);

    int   j[CH];
    float ax[CH], ay[CH], az[CH];
    #pragma unroll
    for (int k = 0; k < CH; ++k) {
        float4 e = C[i0 + k * sub];
        ax[k] = e.x; ay[k] = e.y; az[k] = e.z;
        j[k] = __float_as_int(e.w);
    }

    bool any = false;
    #pragma unroll
    for (int k = 0; k < CH; ++k)
        any |= BASE ? (j[k] != NNODES) : (j[k] >= lo);

    while (any) {
        float4 e[CH];
        #pragma unroll
        for (int k = 0; k < CH; ++k) {
            bool act = BASE ? (j[k] != NNODES) : (j[k] >= lo);
            e[k] = C[act ? j[k] : 0];
        }
        any = false;
        #pragma unroll
        for (int k = 0; k < CH; ++k) {
            bool act = BASE ? (j[k] != NNODES) : (j[k] >= lo);
            if (act) {
                ax[k] += e[k].x; ay[k] += e[k].y; az[k] += e[k].z;
                j[k] = __float_as_int(e[k].w);
            }
            any |= BASE ? (j[k] != NNODES) : (j[k] >= lo);
        }
    }

    if (BASE) {
        #pragma unroll
        for (int k = 0; k < CH; ++k) {
            half4 h = {(_Float16)ax[k], (_Float16)ay[k], (_Float16)az[k], (_Float16)0.f};
            F[i0 + k * sub] = h;
        }
    } else {
        half4 fp[CH];
        #pragma unroll
        for (int k = 0; k < CH; ++k) fp[k] = F[j[k]];   // finalized ancestors
        #pragma unroll
        for (int k = 0; k < CH; ++k) {
            float fx = ax[k] + (float)fp[k].x;
            float fy = ay[k] + (float)fp[k].y;
            float fz = az[k] + (float)fp[k].z;
            half4 h = {(_Float16)fx, (_Float16)fy, (_Float16)fz, (_Float16)0.f};
            F[i0 + k * sub] = h;
        }
    }
}

// Kernel 3: pixel gather. fp16 table = 2MB/tree -> ~3MB per XCD, L2-resident.
// 8 px/thread, XCD-swizzled, three coalesced fp32 output streams.
__global__ __launch_bounds__(256) void k_gather(
    const half4* __restrict__ f,           // (BC*N)
    const int*   __restrict__ pixel_node,  // (BC, HW)
    float* __restrict__ out)               // (BC, 3, HW)
{
    int w = xcd_swizzle(blockIdx.x, gridDim.x);
    size_t gp = (size_t)w * 2048 + (size_t)threadIdx.x * 8;
    int bc = (int)(gp >> 20);              // HWPIX = 2^20
    int p  = (int)(gp & (HWPIX - 1));
    const int4* pn4 = (const int4*)(pixel_node + gp);
    int4 pa = pn4[0], pb = pn4[1];
    const half4* fb = f + ((size_t)bc << 18);
    half4 f0 = fb[pa.x], f1 = fb[pa.y], f2 = fb[pa.z], f3 = fb[pa.w];
    half4 f4 = fb[pb.x], f5 = fb[pb.y], f6 = fb[pb.z], f7 = fb[pb.w];
    float* o = out + (size_t)bc * 3 * HWPIX + p;
    *(float4*)(o)                 = make_float4(f0.x, f1.x, f2.x, f3.x);
    *(float4*)(o + 4)             = make_float4(f4.x, f5.x, f6.x, f7.x);
    *(float4*)(o + HWPIX)         = make_float4(f0.y, f1.y, f2.y, f3.y);
    *(float4*)(o + HWPIX + 4)     = make_float4(f4.y, f5.y, f6.y, f7.y);
    *(float4*)(o + 2 * HWPIX)     = make_float4(f0.z, f1.z, f2.z, f3.z);
    *(float4*)(o + 2 * HWPIX + 4) = make_float4(f4.z, f5.z, f6.z, f7.z);
}

extern "C" void kernel_launch(void* const* d_in, const int* in_sizes, int n_in,
                              void* d_out, int out_size, void* d_ws, size_t ws_size,
                              hipStream_t stream) {
    const float* attrs      = (const float*)d_in[0];
    const float* residue    = (const float*)d_in[1];
    const float* W0         = (const float*)d_in[2];
    const float* W1         = (const float*)d_in[3];
    const float* W2         = (const float*)d_in[4];
    const float* b0         = (const float*)d_in[5];
    const float* b1         = (const float*)d_in[6];
    const float* b2         = (const float*)d_in[7];
    const int*   parent     = (const int*)d_in[8];
    const int*   pixel_node = (const int*)d_in[9];
    float* out = (float*)d_out;

    const size_t total_nodes = (size_t)BC * NNODES;       // 3,145,728
    float4* contrib = (float4*)d_ws;                      // 50.3 MB
    half4*  ftab    = (half4*)(contrib + total_nodes);    // 25.2 MB

    // Kernel 1: contrib + packed parent (4 nodes/thread)
    k_contrib<<<(int)(total_nodes / 4 / 256), 256, 0, stream>>>(
        attrs, residue, parent, W0, W1, W2, b0, b1, b2, contrib);

    // Kernel 2: geometric chunks with multi-chain ILP
    k_scan<1, true ><<< 4096 * BC / 256,          256, 0, stream>>>(contrib, ftab, 0,     4096);
    k_scan<4, false><<< 12288 / 4 * BC / 256,     256, 0, stream>>>(contrib, ftab, 4096,  12288);
    k_scan<4, false><<< 49152 / 4 * BC / 256,     256, 0, stream>>>(contrib, ftab, 16384, 49152);
    k_scan<8, false><<< 196608 / 8 * BC / 256,    256, 0, stream>>>(contrib, ftab, 65536, 196608);

    // Kernel 3: pixel gather (8 px/thread)
    k_gather<<<(int)((size_t)BC * HWPIX / 2048), 256, 0, stream>>>(
        ftab, pixel_node, out);
}